// Round 5
// baseline (612.968 us; speedup 1.0000x reference)
//
#include <hip/hip_runtime.h>

// FlowExp: v = flow/2^8; repeat 8x: v <- trilinear_pull(v, identity + v)
// Invariant: ||v||inf <= max|flow|/256 ~ 0.023 < 1 for all steps (each step is
// a convex combination of previous values, zero-masked outside). Hence
// floor(x+vx) is x-1 (vx<0) or x (vx>=0): the gather needs NO clamps, only a
// sign test, and a halo of 1 in LDS always covers both corners. Out-of-bounds
// samples are handled by folding the inb mask into the z-weights (weights 0).
//
// LDS tile 32x8x8 (+1 halo -> 34x10x10), SoA by channel. Staging iterates
// voxels (one 12B global load + 3 stride-1 conflict-free ds_writes), border
// clamping only in border blocks (wave-uniform branch). Gather: 1 vaddr + 24
// immediate-offset LDS reads (compiler merges to ds_read2_b32) + 24 FMA.

#define BB 2
#define DD 160
#define HH 192
#define WW 160

constexpr int PLANE = DD * HH * WW;     // 4,915,200
constexpr int TX = 32, TY = 8, TZ = 8;
constexpr int SX = TX + 2, SY = TY + 2, SZ = TZ + 2;   // 34 x 10 x 10
constexpr int SYX = SY * SX;            // 340
constexpr int NW  = SZ * SYX;           // 3400
constexpr int NITER = (NW + 255) / 256; // 14

// IN_FMT : 0 = planar (B,3,D,H,W) scaled by `scale` (step 1 reads flow)
//          1 = packed interleaved (B,D,H,W,3)
// OUT_FMT: 0 = planar (final step), 1 = packed
template<int IN_FMT, int OUT_FMT>
__global__ __launch_bounds__(256, 3) void flow_step(const float* __restrict__ vin,
                                                    float* __restrict__ vout,
                                                    float scale) {
    __shared__ float lds[3 * NW];
    const int tid = threadIdx.x;
    const int x0 = blockIdx.x * TX;
    const int y0 = blockIdx.y * TY;
    const int b  = blockIdx.z / (DD / TZ);
    const int z0 = (blockIdx.z % (DD / TZ)) * TZ;
    const bool border = (x0 == 0) | (x0 + TX >= WW) |
                        (y0 == 0) | (y0 + TY >= HH) |
                        (z0 == 0) | (z0 + TZ >= DD);

    // ---- stage tile+halo: one voxel (3 floats) per element, SoA in LDS ----
    const int gb0 = ((z0 - 1) * HH + (y0 - 1)) * WW + (x0 - 1);  // interior base (in-batch)
    #pragma unroll
    for (int k = 0; k < NITER; ++k) {
        int vox = tid + k * 256;
        vox = min(vox, NW - 1);              // tail: duplicate write, same value
        const int szi = vox / SYX;
        const int r   = vox - szi * SYX;
        const int syi = r / SX;
        const int sxi = r - syi * SX;
        int pa;                               // voxel offset within batch b
        if (!border) {
            pa = gb0 + szi * (HH * WW) + syi * WW + sxi;
        } else {
            const int gz = min(max(z0 - 1 + szi, 0), DD - 1);
            const int gy = min(max(y0 - 1 + syi, 0), HH - 1);
            const int gx = min(max(x0 - 1 + sxi, 0), WW - 1);
            pa = (gz * HH + gy) * WW + gx;
        }
        float c0, c1, c2;
        if (IN_FMT == 0) {
            const float* bp = vin + (size_t)b * 3 * PLANE + pa;
            c0 = bp[0] * scale; c1 = bp[PLANE] * scale; c2 = bp[2 * PLANE] * scale;
        } else {
            float t[3];
            __builtin_memcpy(t, vin + ((size_t)b * PLANE + pa) * 3, 12);
            c0 = t[0]; c1 = t[1]; c2 = t[2];
        }
        lds[vox]          = c0;   // stride-1 across lanes: conflict-free
        lds[NW + vox]     = c1;
        lds[2 * NW + vox] = c2;
    }
    __syncthreads();

    // ---- gather: 8 output voxels per thread (zz loop) ----
    const int tx = tid & (TX - 1);
    const int ty = tid >> 5;
    const int x = x0 + tx, y = y0 + ty;

    for (int zz = 0; zz < TZ; ++zz) {
        const int z = z0 + zz;
        const int so = ((zz + 1) * SY + (ty + 1)) * SX + (tx + 1);
        const float vz = lds[so], vy = lds[NW + so], vx = lds[2 * NW + so];
        const float cz = (float)z + vz, cy = (float)y + vy, cx = (float)x + vx;

        const bool jz = vz < 0.f, jy = vy < 0.f, jx = vx < 0.f;
        const float gzf = jz ? vz + 1.f : vz;   // == cz - floor(cz) up to ulp(cz)
        const float gyf = jy ? vy + 1.f : vy;
        const float gxf = jx ? vx + 1.f : vx;

        const bool inb = (cz >= 0.f) & (cz <= (float)(DD - 1)) &
                         (cy >= 0.f) & (cy <= (float)(HH - 1)) &
                         (cx >= 0.f) & (cx <= (float)(WW - 1));
        const float m = inb ? 1.f : 0.f;
        const float wz1 = gzf * m, wz0 = m - wz1;
        const float wy1 = gyf,     wy0 = 1.f - gyf;
        const float wx1 = gxf,     wx0 = 1.f - gxf;

        const int sb = ((so - (jx ? 1 : 0)) - (jy ? SX : 0)) - (jz ? SYX : 0);

        float oz = 0.f, oy = 0.f, ox = 0.f;
        #pragma unroll
        for (int dz = 0; dz < 2; ++dz) {
            const float wzv = dz ? wz1 : wz0;
            #pragma unroll
            for (int dy = 0; dy < 2; ++dy) {
                const float wzy = wzv * (dy ? wy1 : wy0);
                const float w0 = wzy * wx0, w1 = wzy * wx1;
                const int o = sb + dz * SYX + dy * SX;   // all offsets vs sb are imm
                oz += lds[o] * w0;              oy += lds[NW + o] * w0;
                ox += lds[2 * NW + o] * w0;
                oz += lds[o + 1] * w1;          oy += lds[NW + o + 1] * w1;
                ox += lds[2 * NW + o + 1] * w1;
            }
        }

        if (OUT_FMT == 0) {
            float* bp = vout + (size_t)b * 3 * PLANE + (z * HH + y) * WW + x;
            bp[0] = oz; bp[PLANE] = oy; bp[2 * PLANE] = ox;
        } else {
            float t[3] = { oz, oy, ox };
            __builtin_memcpy(vout + ((size_t)((b * DD + z) * HH + y) * WW + x) * 3, t, 12);
        }
    }
}

extern "C" void kernel_launch(void* const* d_in, const int* in_sizes, int n_in,
                              void* d_out, int out_size, void* d_ws, size_t ws_size,
                              hipStream_t stream) {
    const float* flow = (const float*)d_in[0];
    float* out = (float*)d_out;   // doubles as packed scratch for even steps
    float* wsA = (float*)d_ws;    // packed scratch (118 MB)

    dim3 blk(256);
    dim3 grd(WW / TX, HH / TY, (DD / TZ) * BB);   // 5 x 24 x 40
    const float s = 1.f / 256.f;                  // 1 / 2^NSTEPS

    flow_step<0, 1><<<grd, blk, 0, stream>>>(flow, wsA, s);
    flow_step<1, 1><<<grd, blk, 0, stream>>>(wsA, out, 1.f);
    flow_step<1, 1><<<grd, blk, 0, stream>>>(out, wsA, 1.f);
    flow_step<1, 1><<<grd, blk, 0, stream>>>(wsA, out, 1.f);
    flow_step<1, 1><<<grd, blk, 0, stream>>>(out, wsA, 1.f);
    flow_step<1, 1><<<grd, blk, 0, stream>>>(wsA, out, 1.f);
    flow_step<1, 1><<<grd, blk, 0, stream>>>(out, wsA, 1.f);
    flow_step<1, 0><<<grd, blk, 0, stream>>>(wsA, out, 1.f);
}